// Round 3
// baseline (689.614 us; speedup 1.0000x reference)
//
#include <hip/hip_runtime.h>
#include <stdint.h>

// ImageWiseConv2d: per-sample conv, images [64,64,128,128] f32, kernels [64,64,3,3] f32
// out [64,1,126,126] f32 (VALID, stride 1).
//
// R2: kill the R1 scratch spill (WRITE_SIZE 663MB, VALUBusy 4.3% at VGPR=64).
//  - Row-streaming FMA: no f[4][8] staging array; ~40 live VGPRs.
//  - global_load_lds width=16 staging: no VGPR round-trip, no prefetch registers.
//  - LDS unpadded 18x128 per buffer (global_load_lds is wave-uniform base + lane*16;
//    padding would break the mapping). Stride 128: each 8-lane group covers 32 banks.
//  - Split-K NG=4 -> 2048 blocks = 8 blocks/CU; launch_bounds(256,8) -> 64-VGPR budget,
//    32 waves/CU; out-of-phase blocks cover the per-channel barrier vmcnt drain.

#define NS   64
#define CCH  64
#define HH   128
#define WW   128
#define OHH  126
#define OWW  126
#define TH   16      // output rows per tile
#define IR   18      // input rows per tile (halo 2)
#define NG   4       // channel groups (split-K)
#define CPG  16      // channels per group
#define PSTR 128     // padded partial row stride (floats)
#define BUFD (IR * WW)     // 2304 dwords per LDS buffer
#define BUFP (BUFD + 8)    // tail pad: harmless over-read at (row17, col>=124)

typedef const __attribute__((address_space(1))) void  ga_void;
typedef __attribute__((address_space(3))) void        ls_void;

__global__ __launch_bounds__(256, 8)
void ImageWiseConv2d_main(const float* __restrict__ img,
                          const float* __restrict__ ker,
                          float* __restrict__ part)
{
    __shared__ float buf[2][BUFP];

    const int tid = threadIdx.x;
    const int bx  = blockIdx.x;          // 0..2047
    const int bt  = bx & 7;              // row-tile
    const int n   = (bx >> 3) & 63;      // sample
    const int g   = bx >> 9;             // channel group 0..3
    const int h0  = bt * TH;

    // ---- staging mapping: lane tid stages 16B at chunk dword 4*tid ----
    const int srow = tid >> 5;           // 0..7 within chunk
    const int scol = (tid & 31) << 2;    // dword col
    const int wv   = tid >> 6;           // wave 0..3
    const float* gc0 = img + (((n * CCH + g * CPG) * HH) + h0 + srow) * WW + scol;
    // chunk2 (tile rows 16..17, wave 0 only): clamp source row (clamped rows feed
    // only discarded outputs at bt=7)
    int r2 = h0 + 16 + srow;
    if (r2 > HH - 1) r2 = HH - 1;
    const float* gc2 = img + (((n * CCH + g * CPG) * HH) + r2) * WW + scol;

    // ---- compute mapping: thread = 2 out rows x 4 out cols ----
    const int r0 = (tid >> 5) << 1;      // 0..14
    const int c0 = (tid & 31) << 2;      // 0..124

    float acc0[4] = {0.f, 0.f, 0.f, 0.f};
    float acc1[4] = {0.f, 0.f, 0.f, 0.f};

    // ---- stage channel 0 ----
    {
        ls_void* l0 = (ls_void*)&buf[0][wv * 256];
        ls_void* l1 = (ls_void*)&buf[0][1024 + wv * 256];
        __builtin_amdgcn_global_load_lds((ga_void*)gc0, l0, 16, 0, 0);
        __builtin_amdgcn_global_load_lds((ga_void*)(gc0 + 8 * WW), l1, 16, 0, 0);
        if (tid < 64) {
            ls_void* l2 = (ls_void*)&buf[0][2048];
            __builtin_amdgcn_global_load_lds((ga_void*)gc2, l2, 16, 0, 0);
        }
    }
    __syncthreads();

    const float* __restrict__ kb = ker + (n * CCH + g * CPG) * 9;  // block-uniform

    for (int c = 0; c < CPG; ++c) {
        // prefetch channel c+1 straight into the other LDS buffer
        if (c + 1 < CPG) {
            const int b = (c + 1) & 1;
            const int gof = (c + 1) * HH * WW;
            ls_void* l0 = (ls_void*)&buf[b][wv * 256];
            ls_void* l1 = (ls_void*)&buf[b][1024 + wv * 256];
            __builtin_amdgcn_global_load_lds((ga_void*)(gc0 + gof), l0, 16, 0, 0);
            __builtin_amdgcn_global_load_lds((ga_void*)(gc0 + gof + 8 * WW), l1, 16, 0, 0);
            if (tid < 64) {
                ls_void* l2 = (ls_void*)&buf[b][2048];
                __builtin_amdgcn_global_load_lds((ga_void*)(gc2 + gof), l2, 16, 0, 0);
            }
        }

        // weights (block-uniform -> scalar loads)
        float w0 = kb[c * 9 + 0], w1 = kb[c * 9 + 1], w2 = kb[c * 9 + 2];
        float w3 = kb[c * 9 + 3], w4 = kb[c * 9 + 4], w5 = kb[c * 9 + 5];
        float w6 = kb[c * 9 + 6], w7 = kb[c * 9 + 7], w8 = kb[c * 9 + 8];

        const float* bc = buf[c & 1];

        // row-streaming: load 6 floats of one input row, fold into accumulators
        #pragma unroll
        for (int k = 0; k < 4; ++k) {
            const float* rp = &bc[(r0 + k) * WW + c0];
            float4 va = *(const float4*)rp;
            float2 vb = *(const float2*)(rp + 4);
            float v0 = va.x, v1 = va.y, v2 = va.z, v3 = va.w, v4 = vb.x, v5 = vb.y;

            if (k < 3) {  // feeds acc0 with kernel row k
                const float a0 = (k == 0) ? w0 : (k == 1) ? w3 : w6;
                const float a1 = (k == 0) ? w1 : (k == 1) ? w4 : w7;
                const float a2 = (k == 0) ? w2 : (k == 1) ? w5 : w8;
                acc0[0] = fmaf(a0, v0, acc0[0]); acc0[0] = fmaf(a1, v1, acc0[0]); acc0[0] = fmaf(a2, v2, acc0[0]);
                acc0[1] = fmaf(a0, v1, acc0[1]); acc0[1] = fmaf(a1, v2, acc0[1]); acc0[1] = fmaf(a2, v3, acc0[1]);
                acc0[2] = fmaf(a0, v2, acc0[2]); acc0[2] = fmaf(a1, v3, acc0[2]); acc0[2] = fmaf(a2, v4, acc0[2]);
                acc0[3] = fmaf(a0, v3, acc0[3]); acc0[3] = fmaf(a1, v4, acc0[3]); acc0[3] = fmaf(a2, v5, acc0[3]);
            }
            if (k > 0) {  // feeds acc1 with kernel row k-1
                const float a0 = (k == 1) ? w0 : (k == 2) ? w3 : w6;
                const float a1 = (k == 1) ? w1 : (k == 2) ? w4 : w7;
                const float a2 = (k == 1) ? w2 : (k == 2) ? w5 : w8;
                acc1[0] = fmaf(a0, v0, acc1[0]); acc1[0] = fmaf(a1, v1, acc1[0]); acc1[0] = fmaf(a2, v2, acc1[0]);
                acc1[1] = fmaf(a0, v1, acc1[1]); acc1[1] = fmaf(a1, v2, acc1[1]); acc1[1] = fmaf(a2, v3, acc1[1]);
                acc1[2] = fmaf(a0, v2, acc1[2]); acc1[2] = fmaf(a1, v3, acc1[2]); acc1[2] = fmaf(a2, v4, acc1[2]);
                acc1[3] = fmaf(a0, v3, acc1[3]); acc1[3] = fmaf(a1, v4, acc1[3]); acc1[3] = fmaf(a2, v5, acc1[3]);
            }
        }

        __syncthreads();   // drains this wave's global_load_lds; other blocks cover
    }

    // ---- store 2x4 partials (padded stride 128 -> unguarded float4 cols) ----
    const int oh0 = h0 + r0;
    if (oh0 < OHH) {
        float* pp = part + (((g * NS + n) * OHH) + oh0) * PSTR + c0;
        *(float4*)pp = make_float4(acc0[0], acc0[1], acc0[2], acc0[3]);
    }
    if (oh0 + 1 < OHH) {
        float* pp = part + (((g * NS + n) * OHH) + oh0 + 1) * PSTR + c0;
        *(float4*)pp = make_float4(acc1[0], acc1[1], acc1[2], acc1[3]);
    }
}

__global__ __launch_bounds__(256)
void ImageWiseConv2d_reduce(const float* __restrict__ part,
                            float* __restrict__ out)
{
    const int i = blockIdx.x * 256 + threadIdx.x;
    const int total = NS * OHH * OWW;          // 1,016,064
    if (i >= total) return;
    const int n  = i / (OHH * OWW);
    const int r  = i - n * (OHH * OWW);
    const int oh = r / OWW;
    const int ow = r - oh * OWW;
    const int gs = NS * OHH * PSTR;            // per-group stride
    const int pb = (n * OHH + oh) * PSTR + ow;
    out[i] = part[pb] + part[pb + gs] + part[pb + 2 * gs] + part[pb + 3 * gs];
}

extern "C" void kernel_launch(void* const* d_in, const int* in_sizes, int n_in,
                              void* d_out, int out_size, void* d_ws, size_t ws_size,
                              hipStream_t stream) {
    const float* img = (const float*)d_in[0];   // [64,64,128,128] f32
    const float* ker = (const float*)d_in[1];   // [64,64,3,3] f32
    float* out  = (float*)d_out;                // [64,1,126,126] f32
    float* part = (float*)d_ws;                 // [4][64][126][128] f32 = 16.5 MB

    ImageWiseConv2d_main<<<dim3(NG * NS * 8), dim3(256), 0, stream>>>(img, ker, part);

    const int total = NS * OHH * OWW;
    ImageWiseConv2d_reduce<<<dim3((total + 255) / 256), dim3(256), 0, stream>>>(part, out);
}

// Round 4
// 356.695 us; speedup vs baseline: 1.9333x; 1.9333x over previous
//
#include <hip/hip_runtime.h>

// ImageWiseConv2d: per-sample conv, images [64,64,128,128] f32, kernels [64,64,3,3] f32
// out [64,1,126,126] f32 (VALID, stride 1).
//
// R3: direct-from-global streaming, NO LDS, NO barriers, NO split-K, no workspace.
// Lessons: R1/R2 regressions were scratch spill from tight launch_bounds VGPR budgets
// (WRITE_SIZE 663/841 MB); harness fixed overhead is ~258 us, so R0's kernel was ~100 us.
// Each thread computes a 2x4 output patch, loading its own 4 rows x 8 cols per channel
// (4x float4 + 4x float2 = 96 B). Redundancy (~3x) is served by L1/L2 (~0.85 GB total,
// well under L1 aggregate BW); HBM sees each line once (~290 MB) -> HBM-bound ~50 us.
// No __syncthreads -> no vmcnt(0) drain; latency hidden by reg double-buffer + 8 waves/CU.
// launch_bounds(256,2): VGPR budget 256 -- generous, zero spill risk (grid caps us at
// 2 blocks/CU anyway).

#define NS   64
#define CCH  64
#define HH   128
#define WW   128
#define OHH  126
#define OWW  126
#define CHS  (HH * WW)   // 16384 floats per channel

__global__ __launch_bounds__(256, 2)
void ImageWiseConv2d_direct(const float* __restrict__ img,
                            const float* __restrict__ ker,
                            float* __restrict__ out)
{
    const int tid = threadIdx.x;
    const int bx  = blockIdx.x;          // 0..511
    const int bt  = bx & 7;              // row tile (16 output rows)
    const int n   = bx >> 3;             // sample
    const int h0  = bt * 16;

    const int r0 = (tid >> 5) << 1;      // patch top output row within tile: 0..14
    const int c0 = (tid & 31) << 2;      // patch left output col: 0..124

    // input rows ihr..ihr+3; clamp so we never read past row 127 (clamped case is
    // bt=7,r0=14 whose outputs are discarded)
    int ihr = h0 + r0;
    if (ihr > HH - 4) ihr = HH - 4;
    // cols c0+4,c0+5 via float2; for c0=124 clamp to cols 126,127 (in-row; values
    // only feed output cols 126/127 which are never stored)
    const int bOff = (c0 < 124) ? 4 : 2;

    const float* p0 = img + (((n * CCH) * HH) + ihr) * WW + c0;
    const float* kp = ker + (n * CCH) * 9;   // block-uniform -> scalar loads

    float a00 = 0.f, a01 = 0.f, a02 = 0.f, a03 = 0.f;
    float a10 = 0.f, a11 = 0.f, a12 = 0.f, a13 = 0.f;

    // current-channel patch registers
    float4 A0, A1, A2, A3;
    float2 B0, B1, B2, B3;
    A0 = *(const float4*)(p0);
    A1 = *(const float4*)(p0 + WW);
    A2 = *(const float4*)(p0 + 2 * WW);
    A3 = *(const float4*)(p0 + 3 * WW);
    B0 = *(const float2*)(p0 + bOff);
    B1 = *(const float2*)(p0 + WW + bOff);
    B2 = *(const float2*)(p0 + 2 * WW + bOff);
    B3 = *(const float2*)(p0 + 3 * WW + bOff);

    for (int c = 0; c < CCH; ++c) {
        // prefetch next channel into fresh registers (no barrier anywhere)
        float4 nA0, nA1, nA2, nA3;
        float2 nB0, nB1, nB2, nB3;
        const bool more = (c + 1 < CCH);
        if (more) {
            const float* q = p0 + (c + 1) * CHS;
            nA0 = *(const float4*)(q);
            nA1 = *(const float4*)(q + WW);
            nA2 = *(const float4*)(q + 2 * WW);
            nA3 = *(const float4*)(q + 3 * WW);
            nB0 = *(const float2*)(q + bOff);
            nB1 = *(const float2*)(q + WW + bOff);
            nB2 = *(const float2*)(q + 2 * WW + bOff);
            nB3 = *(const float2*)(q + 3 * WW + bOff);
        }

        const float w0 = kp[c * 9 + 0], w1 = kp[c * 9 + 1], w2 = kp[c * 9 + 2];
        const float w3 = kp[c * 9 + 3], w4 = kp[c * 9 + 4], w5 = kp[c * 9 + 5];
        const float w6 = kp[c * 9 + 6], w7 = kp[c * 9 + 7], w8 = kp[c * 9 + 8];

        // row 0 -> acc0 (kernel row 0)
        {
            const float v0 = A0.x, v1 = A0.y, v2 = A0.z, v3 = A0.w, v4 = B0.x, v5 = B0.y;
            a00 = fmaf(w0, v0, a00); a00 = fmaf(w1, v1, a00); a00 = fmaf(w2, v2, a00);
            a01 = fmaf(w0, v1, a01); a01 = fmaf(w1, v2, a01); a01 = fmaf(w2, v3, a01);
            a02 = fmaf(w0, v2, a02); a02 = fmaf(w1, v3, a02); a02 = fmaf(w2, v4, a02);
            a03 = fmaf(w0, v3, a03); a03 = fmaf(w1, v4, a03); a03 = fmaf(w2, v5, a03);
        }
        // row 1 -> acc0 (kr 1), acc1 (kr 0)
        {
            const float v0 = A1.x, v1 = A1.y, v2 = A1.z, v3 = A1.w, v4 = B1.x, v5 = B1.y;
            a00 = fmaf(w3, v0, a00); a00 = fmaf(w4, v1, a00); a00 = fmaf(w5, v2, a00);
            a01 = fmaf(w3, v1, a01); a01 = fmaf(w4, v2, a01); a01 = fmaf(w5, v3, a01);
            a02 = fmaf(w3, v2, a02); a02 = fmaf(w4, v3, a02); a02 = fmaf(w5, v4, a02);
            a03 = fmaf(w3, v3, a03); a03 = fmaf(w4, v4, a03); a03 = fmaf(w5, v5, a03);
            a10 = fmaf(w0, v0, a10); a10 = fmaf(w1, v1, a10); a10 = fmaf(w2, v2, a10);
            a11 = fmaf(w0, v1, a11); a11 = fmaf(w1, v2, a11); a11 = fmaf(w2, v3, a11);
            a12 = fmaf(w0, v2, a12); a12 = fmaf(w1, v3, a12); a12 = fmaf(w2, v4, a12);
            a13 = fmaf(w0, v3, a13); a13 = fmaf(w1, v4, a13); a13 = fmaf(w2, v5, a13);
        }
        // row 2 -> acc0 (kr 2), acc1 (kr 1)
        {
            const float v0 = A2.x, v1 = A2.y, v2 = A2.z, v3 = A2.w, v4 = B2.x, v5 = B2.y;
            a00 = fmaf(w6, v0, a00); a00 = fmaf(w7, v1, a00); a00 = fmaf(w8, v2, a00);
            a01 = fmaf(w6, v1, a01); a01 = fmaf(w7, v2, a01); a01 = fmaf(w8, v3, a01);
            a02 = fmaf(w6, v2, a02); a02 = fmaf(w7, v3, a02); a02 = fmaf(w8, v4, a02);
            a03 = fmaf(w6, v3, a03); a03 = fmaf(w7, v4, a03); a03 = fmaf(w8, v5, a03);
            a10 = fmaf(w3, v0, a10); a10 = fmaf(w4, v1, a10); a10 = fmaf(w5, v2, a10);
            a11 = fmaf(w3, v1, a11); a11 = fmaf(w4, v2, a11); a11 = fmaf(w5, v3, a11);
            a12 = fmaf(w3, v2, a12); a12 = fmaf(w4, v3, a12); a12 = fmaf(w5, v4, a12);
            a13 = fmaf(w3, v3, a13); a13 = fmaf(w4, v4, a13); a13 = fmaf(w5, v5, a13);
        }
        // row 3 -> acc1 (kr 2)
        {
            const float v0 = A3.x, v1 = A3.y, v2 = A3.z, v3 = A3.w, v4 = B3.x, v5 = B3.y;
            a10 = fmaf(w6, v0, a10); a10 = fmaf(w7, v1, a10); a10 = fmaf(w8, v2, a10);
            a11 = fmaf(w6, v1, a11); a11 = fmaf(w7, v2, a11); a11 = fmaf(w8, v3, a11);
            a12 = fmaf(w6, v2, a12); a12 = fmaf(w7, v3, a12); a12 = fmaf(w8, v4, a12);
            a13 = fmaf(w6, v3, a13); a13 = fmaf(w7, v4, a13); a13 = fmaf(w8, v5, a13);
        }

        if (more) {
            A0 = nA0; A1 = nA1; A2 = nA2; A3 = nA3;
            B0 = nB0; B1 = nB1; B2 = nB2; B3 = nB3;
        }
    }

    // ---- store 2x4 (float2 pairs: out rows are 8B- but not 16B-aligned) ----
    const int oh0 = h0 + r0;
    if (oh0 < OHH) {           // oh0 invalid only for bt=7,r0=14, where oh0+1 is too
        float* o0 = out + (n * OHH + oh0) * OWW + c0;
        float* o1 = o0 + OWW;
        *(float2*)o0 = make_float2(a00, a01);
        *(float2*)o1 = make_float2(a10, a11);
        if (c0 < 124) {
            *(float2*)(o0 + 2) = make_float2(a02, a03);
            *(float2*)(o1 + 2) = make_float2(a12, a13);
        }
    }
}

extern "C" void kernel_launch(void* const* d_in, const int* in_sizes, int n_in,
                              void* d_out, int out_size, void* d_ws, size_t ws_size,
                              hipStream_t stream) {
    const float* img = (const float*)d_in[0];   // [64,64,128,128] f32
    const float* ker = (const float*)d_in[1];   // [64,64,3,3] f32
    float* out = (float*)d_out;                 // [64,1,126,126] f32

    ImageWiseConv2d_direct<<<dim3(NS * 8), dim3(256), 0, stream>>>(img, ker, out);
}